// Round 7
// baseline (249.086 us; speedup 1.0000x reference)
//
#include <hip/hip_runtime.h>

#define EMB 2048
#define NH 16
#define NKV 4
#define HD 128
#define SLEN 2048
#define BSZ 2
#define MROWS (BSZ * SLEN) // 4096

// element offsets within the fused QKV output buffer
#define QOFF (BSZ * NH * SLEN * HD)   // 8388608
#define KOFF (BSZ * NKV * SLEN * HD)  // 2097152

typedef __attribute__((ext_vector_type(8))) short bf16x8;
typedef __attribute__((ext_vector_type(4))) float f32x4;
typedef __attribute__((ext_vector_type(2))) float f32x2;
typedef __attribute__((ext_vector_type(4))) short s16x4;

__device__ __forceinline__ short f2bf(float f) {
  union { float f; unsigned u; } v; v.f = f;
  unsigned r = (v.u + 0x7fffu + ((v.u >> 16) & 1u)) >> 16;
  return (short)r;
}

// ---------------- RoPE cos/sin table: [SLEN][64] ----------------
__global__ void rope_tab_k(f32x2* __restrict__ tab) {
  int i = blockIdx.x * blockDim.x + threadIdx.x;
  if (i >= SLEN * 64) return;
  int s = i >> 6, j = i & 63;
  float freq = exp2f(-(float)j * (13.287712379549449f / 64.0f));
  float ang = (float)s * freq;
  float sv, cv;
  sincosf(ang, &sv, &cv);
  f32x2 cs; cs[0] = cv; cs[1] = sv;
  tab[i] = cs;
}

// ---------------- fp32 -> bf16 cast (vectorized) ----------------
__global__ void cast_bf16_k(const float* __restrict__ in, short* __restrict__ outp, int n) {
  int i = (blockIdx.x * blockDim.x + threadIdx.x) * 4;
  if (i >= n) return;
  f32x4 v = *(const f32x4*)(in + i);
  s16x4 r;
#pragma unroll
  for (int k = 0; k < 4; ++k) r[k] = f2bf(v[k]);
  *(s16x4*)(outp + i) = r;
}

// ---------------- transpose + cast: in (R,C) fp32 -> out (C,R) bf16 ----------------
__global__ void transpose_cast_k(const float* __restrict__ in, short* __restrict__ outp,
                                 int R, int C) {
  __shared__ float t[32][33];
  int c0 = blockIdx.x * 32, r0 = blockIdx.y * 32;
  int tx = threadIdx.x, ty = threadIdx.y; // 32 x 8
#pragma unroll
  for (int i = 0; i < 4; ++i)
    t[ty + i * 8][tx] = in[(size_t)(r0 + ty + i * 8) * C + (c0 + tx)];
  __syncthreads();
#pragma unroll
  for (int i = 0; i < 4; ++i)
    outp[(size_t)(c0 + ty + i * 8) * R + (r0 + tx)] = f2bf(t[tx][ty + i * 8]);
}

#define GLL16(g, l)                                                        \
  __builtin_amdgcn_global_load_lds(                                        \
      (const __attribute__((address_space(1))) void*)(g),                  \
      (__attribute__((address_space(3))) void*)(l), 16, 0, 0)

// ---------------- 128x128 GEMM (2-phase), used for out-proj only ----------------
#define BM 128
#define BN 128
#define BK 32

__global__ __launch_bounds__(256, 2) void gemm_bt_k(
    const short* __restrict__ A, const short* __restrict__ Bt,
    float* __restrict__ Cf, int M, int N, int K) {
  __shared__ short lA[2][BM * BK];
  __shared__ short lB[2][BN * BK];
  int tid = threadIdx.x;
  int lane = tid & 63, wid = tid >> 6;
  int m0 = blockIdx.y * BM, n0 = blockIdx.x * BN;
  int wr = (wid >> 1) * 64, wc = (wid & 1) * 64;
  int l16 = lane & 15, lk = (lane >> 4) * 8;
  (void)M;

  auto stage = [&](int buf, int k0) {
    const short* ga = A + (size_t)m0 * K + k0;
    const short* gb = Bt + (size_t)n0 * K + k0;
#pragma unroll
    for (int i = 0; i < 2; ++i) {
      int cidx = i * 256 + tid;
      int row = cidx >> 2, c8 = (cidx & 3) << 3;
      GLL16(ga + (size_t)row * K + c8, &lA[buf][(size_t)(i * 256 + (tid & 192)) * 8]);
      GLL16(gb + (size_t)row * K + c8, &lB[buf][(size_t)(i * 256 + (tid & 192)) * 8]);
    }
  };

  f32x4 acc[4][4] = {};
  stage(0, 0);
  asm volatile("s_waitcnt vmcnt(0)" ::: "memory");
  __syncthreads();
  int nk = K / BK;
  for (int t = 0; t < nk; ++t) {
    int buf = t & 1;
    if (t + 1 < nk) stage(buf ^ 1, (t + 1) * BK);
    bf16x8 af[4], bfv[4];
#pragma unroll
    for (int m = 0; m < 4; ++m)
      af[m] = *(const bf16x8*)&lA[buf][(wr + m * 16 + l16) * BK + lk];
#pragma unroll
    for (int n = 0; n < 4; ++n)
      bfv[n] = *(const bf16x8*)&lB[buf][(wc + n * 16 + l16) * BK + lk];
#pragma unroll
    for (int m = 0; m < 4; ++m)
#pragma unroll
      for (int n = 0; n < 4; ++n)
        acc[m][n] = __builtin_amdgcn_mfma_f32_16x16x32_bf16(af[m], bfv[n], acc[m][n], 0, 0, 0);
    asm volatile("s_waitcnt vmcnt(0)" ::: "memory");
    __syncthreads();
  }

#pragma unroll
  for (int m = 0; m < 4; ++m)
#pragma unroll
    for (int n = 0; n < 4; ++n)
#pragma unroll
      for (int j = 0; j < 4; ++j) {
        int gm = m0 + wr + m * 16 + (lane >> 4) * 4 + j;
        int gc = n0 + wc + n * 16 + l16;
        Cf[(size_t)gm * N + gc] = acc[m][n][j];
      }
}

// ---------------- 256x256 8-phase QKV GEMM (T2+T3+T4+T5) ----------------
// C(4096,3072) = xb(4096,2048) * wqkvT(3072,2048)^T, fused RoPE-QKV epilogue.
// BK=64 split into two K-half stage units [256 rows][32 k] (16KB each).
// Buffers alternate per K-tile; staging during kt fills buf[(kt+1)&1] whose
// readers finished at kt-1's closing barrier. Each phase: ds_read frags ->
// stage one unit (2 gll/thread) -> barrier -> lgkmcnt(0) -> 16 MFMA -> barrier.
// vmcnt(4) ONLY at phases 2 and 4 (counted, never 0 -> loads span phases).
// Swizzle: byte ^= ((row>>1)&3)<<4 on 64B rows -> 2-way bank aliasing (free).
// RoPE stored INTERLEAVED (rotated pair kept at positions 2j,2j+1): the
// QK dot-product is invariant since Q and K share the permutation; makes
// epilogue stores contiguous. V stored transposed [HD][S] as before.
__global__ __launch_bounds__(512, 1) void gemm_qkv256_k(
    const short* __restrict__ A, const short* __restrict__ Bt,
    short* __restrict__ Cb, const f32x2* __restrict__ rope) {
  __shared__ char sA[2][2][16384]; // [buf][k-half][256 rows x 64B]
  __shared__ char sB[2][2][16384];

  int tid = threadIdx.x, lane = tid & 63, wid = tid >> 6;
  int l16 = lane & 15, lk4 = lane >> 4;
  int wr2 = wid >> 2, wc2 = wid & 3;
  int m0 = blockIdx.y * 256, n0 = blockIdx.x * 256;
  const int K2B = EMB * 2;
  const char* Ab = (const char*)A;
  const char* Bb = (const char*)Bt;

  // stage one K-half unit: global [r0g + 0..255][kt*64 + kh*32 + 0..31] elems
  auto stU = [&](const char* gbase, int r0g, char* lunit, int kt, int kh) {
#pragma unroll
    for (int r2 = 0; r2 < 2; ++r2) {
      int X = tid * 16 + r2 * 8192;
      int row = X >> 6, cb = X & 63;
      int logical = cb ^ ((((row >> 1) & 3)) << 4); // inverse-swz source (rule #21)
      GLL16(gbase + (size_t)(r0g + row) * K2B + kt * 128 + kh * 64 + logical,
            lunit + X);
    }
  };
  auto ldA = [&](int buf, int m, int kk) {
    int r = wr2 * 128 + m * 16 + l16;
    return *(const bf16x8*)(&sA[buf][kk][0] + r * 64 + ((lk4 * 16) ^ ((((r >> 1) & 3)) << 4)));
  };
  auto ldB = [&](int buf, int n, int kk) {
    int r = wc2 * 64 + n * 16 + l16;
    return *(const bf16x8*)(&sB[buf][kk][0] + r * 64 + ((lk4 * 16) ^ ((((r >> 1) & 3)) << 4)));
  };

  f32x4 acc[8][4] = {};

  // prologue: stage kt0's 4 units; oldest 4 loads = A-Kh0 + B-Kh0
  stU(Ab, m0, &sA[0][0][0], 0, 0);
  stU(Bb, n0, &sB[0][0][0], 0, 0);
  stU(Ab, m0, &sA[0][1][0], 0, 1);
  stU(Bb, n0, &sB[0][1][0], 0, 1);
  asm volatile("s_waitcnt vmcnt(4)" ::: "memory");
  __builtin_amdgcn_s_barrier();

  const int NKT = EMB / 64; // 32
  for (int kt = 0; kt < NKT; ++kt) {
    int buf = kt & 1, nbuf = buf ^ 1;
    int kn = (kt + 1 < NKT) ? kt + 1 : 0; // wrap: keeps vmcnt counts uniform
    bf16x8 fa[8], fb0, fb1;
    // ---- P1: kk0, n0-1 ----
#pragma unroll
    for (int m = 0; m < 8; ++m) fa[m] = ldA(buf, m, 0);
    fb0 = ldB(buf, 0, 0); fb1 = ldB(buf, 1, 0);
    stU(Ab, m0, &sA[nbuf][0][0], kn, 0);
    __builtin_amdgcn_s_barrier();
    asm volatile("s_waitcnt lgkmcnt(0)" ::: "memory");
    __builtin_amdgcn_sched_barrier(0);
    __builtin_amdgcn_s_setprio(1);
#pragma unroll
    for (int m = 0; m < 8; ++m) {
      acc[m][0] = __builtin_amdgcn_mfma_f32_16x16x32_bf16(fa[m], fb0, acc[m][0], 0, 0, 0);
      acc[m][1] = __builtin_amdgcn_mfma_f32_16x16x32_bf16(fa[m], fb1, acc[m][1], 0, 0, 0);
    }
    __builtin_amdgcn_s_setprio(0);
    __builtin_amdgcn_s_barrier();
    // ---- P2: kk0, n2-3 ----
    fb0 = ldB(buf, 2, 0); fb1 = ldB(buf, 3, 0);
    stU(Bb, n0, &sB[nbuf][0][0], kn, 0);
    __builtin_amdgcn_s_barrier();
    asm volatile("s_waitcnt lgkmcnt(0)" ::: "memory");
    __builtin_amdgcn_sched_barrier(0);
    __builtin_amdgcn_s_setprio(1);
#pragma unroll
    for (int m = 0; m < 8; ++m) {
      acc[m][2] = __builtin_amdgcn_mfma_f32_16x16x32_bf16(fa[m], fb0, acc[m][2], 0, 0, 0);
      acc[m][3] = __builtin_amdgcn_mfma_f32_16x16x32_bf16(fa[m], fb1, acc[m][3], 0, 0, 0);
    }
    __builtin_amdgcn_s_setprio(0);
    asm volatile("s_waitcnt vmcnt(4)" ::: "memory"); // kh1 units of THIS kt done
    __builtin_amdgcn_s_barrier();
    // ---- P3: kk1, n2-3 ----
#pragma unroll
    for (int m = 0; m < 8; ++m) fa[m] = ldA(buf, m, 1);
    fb0 = ldB(buf, 2, 1); fb1 = ldB(buf, 3, 1);
    stU(Ab, m0, &sA[nbuf][1][0], kn, 1);
    __builtin_amdgcn_s_barrier();
    asm volatile("s_waitcnt lgkmcnt(0)" ::: "memory");
    __builtin_amdgcn_sched_barrier(0);
    __builtin_amdgcn_s_setprio(1);
#pragma unroll
    for (int m = 0; m < 8; ++m) {
      acc[m][2] = __builtin_amdgcn_mfma_f32_16x16x32_bf16(fa[m], fb0, acc[m][2], 0, 0, 0);
      acc[m][3] = __builtin_amdgcn_mfma_f32_16x16x32_bf16(fa[m], fb1, acc[m][3], 0, 0, 0);
    }
    __builtin_amdgcn_s_setprio(0);
    __builtin_amdgcn_s_barrier();
    // ---- P4: kk1, n0-1 ----
    fb0 = ldB(buf, 0, 1); fb1 = ldB(buf, 1, 1);
    stU(Bb, n0, &sB[nbuf][1][0], kn, 1);
    __builtin_amdgcn_s_barrier();
    asm volatile("s_waitcnt lgkmcnt(0)" ::: "memory");
    __builtin_amdgcn_sched_barrier(0);
    __builtin_amdgcn_s_setprio(1);
#pragma unroll
    for (int m = 0; m < 8; ++m) {
      acc[m][0] = __builtin_amdgcn_mfma_f32_16x16x32_bf16(fa[m], fb0, acc[m][0], 0, 0, 0);
      acc[m][1] = __builtin_amdgcn_mfma_f32_16x16x32_bf16(fa[m], fb1, acc[m][1], 0, 0, 0);
    }
    __builtin_amdgcn_s_setprio(0);
    asm volatile("s_waitcnt vmcnt(4)" ::: "memory"); // next kt's kh0 units done
    __builtin_amdgcn_s_barrier();
  }

  const float SCL2E = 0.08838834764831845f * 1.4426950408889634f;
  // epilogue: C/D layout col = lane&15, row = (lane>>4)*4 + reg
#pragma unroll
  for (int m = 0; m < 8; ++m) {
#pragma unroll
    for (int n = 0; n < 4; ++n) {
      int gc = n0 + wc2 * 64 + n * 16 + l16;
#pragma unroll
      for (int j = 0; j < 4; ++j) {
        float v = acc[m][n][j];
        int gm = m0 + wr2 * 128 + m * 16 + lk4 * 4 + j;
        int pos = gm & (SLEN - 1), bb = gm >> 11;
        if (gc < 2560) { // Q or K: interleaved RoPE
          float p = __shfl_xor(v, 1);
          bool isq = gc < 2048;
          int gcc = isq ? gc : gc - 2048;
          int head = gcc >> 7, d = gcc & 127;
          f32x2 cs = rope[pos * 64 + (d >> 1)];
          float ov = ((d & 1) == 0) ? (v * cs[0] - p * cs[1])
                                    : (p * cs[1] + v * cs[0]);
          if (isq) ov *= SCL2E;
          size_t idx = isq ? (((size_t)(bb * NH + head) * SLEN + pos) * HD + d)
                           : ((size_t)QOFF + ((size_t)(bb * NKV + head) * SLEN + pos) * HD + d);
          Cb[idx] = f2bf(ov);
        } else { // V transposed per (b,kv): [HD][S]
          int gcc = gc - 2560;
          int head = gcc >> 7, d = gcc & 127;
          Cb[(size_t)QOFF + KOFF + ((size_t)(bb * NKV + head) * HD + d) * SLEN + pos] = f2bf(v);
        }
      }
    }
  }
}

// ---------------- flash attention, LDS-cooperative swapped-operand form ----
__global__ __launch_bounds__(512, 3) void flash_k(
    const short* __restrict__ Qb, const short* __restrict__ Kb,
    const short* __restrict__ Vt, short* __restrict__ O) {
  __shared__ short lK[2][64 * 128];   // 64 key rows x 256B
  __shared__ short lV[2][128 * 64];   // 128 dim rows x 128B
  __shared__ short Plds[8][16][64];   // per-wave P: 16 rows x 128B

  int tid = threadIdx.x, lane = tid & 63, wid = tid >> 6;
  int bh = blockIdx.y;
  int b = bh >> 4, h = bh & 15, kv = h & 3; // jnp.tile => h % NKV
  int l16 = lane & 15, lk4 = lane >> 4;
  int qt = (SLEN / 128 - 1) - blockIdx.x; // heavy tiles first
  int qbw = qt * 128 + wid * 16;          // this wave's q-row base

  const short* qptr = Qb + (size_t)(b * NH + h) * SLEN * HD;
  const char* kg = (const char*)(Kb + (size_t)(b * NKV + kv) * SLEN * HD);
  const char* vg = (const char*)(Vt + (size_t)(b * NKV + kv) * HD * SLEN);

  bf16x8 aq[4];
#pragma unroll
  for (int c = 0; c < 4; ++c)
    aq[c] = *(const bf16x8*)(qptr + (size_t)(qbw + l16) * HD + c * 32 + lk4 * 8);

  f32x4 o[8] = {};
  float m = -__builtin_inff();
  float lsum = 0.0f;

  char* myP = (char*)&Plds[wid][0][0];
  int swz = (l16 & 7) << 4;   // 3-bit (P and V: 128B rows)
  int swzk = l16 << 4;        // 4-bit (K: 256B rows)

  auto stageKV = [&](int buf, int k0) {
#pragma unroll
    for (int r = 0; r < 2; ++r) { // K: 16KB
      int X = tid * 16 + r * 8192;
      int row = X >> 8, cb = X & 255;
      GLL16(kg + (size_t)(k0 + row) * 256 + (cb ^ ((row & 15) << 4)),
            (char*)&lK[buf][0] + X);
    }
#pragma unroll
    for (int r = 0; r < 2; ++r) { // V: 16KB
      int X = tid * 16 + r * 8192;
      int row = X >> 7, cb = X & 127;
      GLL16(vg + (size_t)row * (SLEN * 2) + k0 * 2 + (cb ^ ((row & 7) << 4)),
            (char*)&lV[buf][0] + X);
    }
  };

  int ntiles = 2 * (qt + 1);
  stageKV(0, 0);
  asm volatile("s_waitcnt vmcnt(0)" ::: "memory");
  __syncthreads();

  for (int tt = 0; tt < ntiles; ++tt) {
    int buf = tt & 1;
    int k0 = tt * 64;
    if (tt + 1 < ntiles) stageKV(buf ^ 1, (tt + 1) * 64);

    if (k0 < qbw + 16) {
      const char* Kbase = (const char*)&lK[buf][0];
      const char* Vbase = (const char*)&lV[buf][0];
      f32x4 s[4] = {};
      __builtin_amdgcn_s_setprio(1);
#pragma unroll
      for (int c = 0; c < 4; ++c) {
#pragma unroll
        for (int t = 0; t < 4; ++t) {
          bf16x8 bk = *(const bf16x8*)(Kbase + (t * 16 + l16) * 256 + ((c * 64 + lk4 * 16) ^ swzk));
          s[t] = __builtin_amdgcn_mfma_f32_16x16x32_bf16(bk, aq[c], s[t], 0, 0, 0);
        }
      }
      __builtin_amdgcn_s_setprio(0);
      float x[16];
#pragma unroll
      for (int t = 0; t < 4; ++t)
#pragma unroll
        for (int j = 0; j < 4; ++j) x[t * 4 + j] = s[t][j];
      if (k0 + 63 > qbw) {
        int kq = k0 + lk4 * 4 - qbw - l16;
#pragma unroll
        for (int t = 0; t < 4; ++t)
#pragma unroll
          for (int j = 0; j < 4; ++j)
            if (kq + t * 16 + j > 0) x[t * 4 + j] = -3.0e38f;
      }
      float a0 = fmaxf(x[0], x[1]), a1 = fmaxf(x[2], x[3]);
      float a2 = fmaxf(x[4], x[5]), a3 = fmaxf(x[6], x[7]);
      float a4 = fmaxf(x[8], x[9]), a5 = fmaxf(x[10], x[11]);
      float a6 = fmaxf(x[12], x[13]), a7 = fmaxf(x[14], x[15]);
      float b0 = fmaxf(fmaxf(a0, a1), fmaxf(a2, a3));
      float b1 = fmaxf(fmaxf(a4, a5), fmaxf(a6, a7));
      float tm = fmaxf(b0, b1);
      tm = fmaxf(tm, __shfl_xor(tm, 16));
      tm = fmaxf(tm, __shfl_xor(tm, 32));
      float mn = fmaxf(m, tm);
      if (!__all(tm <= m + 8.0f)) {
        float f = __builtin_amdgcn_exp2f(m - mn);
        m = mn;
        lsum *= f;
#pragma unroll
        for (int dt = 0; dt < 8; ++dt) o[dt] *= f;
      }
      float psum = 0.0f;
#pragma unroll
      for (int t = 0; t < 4; ++t) {
        float p0 = __builtin_amdgcn_exp2f(x[t * 4 + 0] - m);
        float p1 = __builtin_amdgcn_exp2f(x[t * 4 + 1] - m);
        float p2 = __builtin_amdgcn_exp2f(x[t * 4 + 2] - m);
        float p3 = __builtin_amdgcn_exp2f(x[t * 4 + 3] - m);
        psum += (p0 + p1) + (p2 + p3);
        unsigned lo, hi;
        asm("v_cvt_pk_bf16_f32 %0, %1, %2" : "=v"(lo) : "v"(p0), "v"(p1));
        asm("v_cvt_pk_bf16_f32 %0, %1, %2" : "=v"(hi) : "v"(p2), "v"(p3));
        unsigned long long dw = ((unsigned long long)hi << 32) | lo;
        *(unsigned long long*)(myP + ((l16 * 128 + t * 32 + lk4 * 8) ^ swz)) = dw;
      }
      lsum += psum;
      asm volatile("s_waitcnt lgkmcnt(0)" ::: "memory");
      __builtin_amdgcn_sched_barrier(0);
      __builtin_amdgcn_s_setprio(1);
#pragma unroll
      for (int hh = 0; hh < 2; ++hh) {
        bf16x8 pa = *(const bf16x8*)(myP + ((l16 * 128 + hh * 64 + lk4 * 16) ^ swz));
#pragma unroll
        for (int dt = 0; dt < 8; ++dt) {
          bf16x8 bv = *(const bf16x8*)(Vbase + (dt * 16 + l16) * 128 + ((hh * 64 + lk4 * 16) ^ swz));
          o[dt] = __builtin_amdgcn_mfma_f32_16x16x32_bf16(bv, pa, o[dt], 0, 0, 0);
        }
      }
      __builtin_amdgcn_s_setprio(0);
    }
    asm volatile("s_waitcnt vmcnt(0)" ::: "memory");
    __syncthreads();
  }
  lsum += __shfl_xor(lsum, 16);
  lsum += __shfl_xor(lsum, 32);
  float inv = 1.0f / lsum;
  size_t ro = ((size_t)(b * SLEN + qbw + l16)) * (NH * HD) + h * HD;
#pragma unroll
  for (int dt = 0; dt < 8; ++dt) {
    s16x4 r;
#pragma unroll
    for (int j = 0; j < 4; ++j) r[j] = f2bf(o[dt][j] * inv);
    *(s16x4*)(O + ro + dt * 16 + lk4 * 4) = r;
  }
}

extern "C" void kernel_launch(void* const* d_in, const int* in_sizes, int n_in,
                              void* d_out, int out_size, void* d_ws, size_t ws_size,
                              hipStream_t stream) {
  const float* x  = (const float*)d_in[0];
  const float* wq = (const float*)d_in[1];
  const float* wk = (const float*)d_in[2];
  const float* wv = (const float*)d_in[3];
  const float* wo = (const float*)d_in[4];
  float* out = (float*)d_out;
  char* ws = (char*)d_ws;
  (void)in_sizes; (void)n_in; (void)out_size; (void)ws_size;

  const size_t MB = 1024 * 1024;
  f32x2* rope   = (f32x2*)(ws);          // 1 MB
  short* xb     = (short*)(ws + 1 * MB); // 16 MB (reused as O)
  short* wqkvT  = (short*)(ws + 17 * MB);// 12 MB: [3072][2048] bf16 B^T
  short* woT    = (short*)(ws + 29 * MB);// 8 MB
  short* QKVb   = (short*)(ws + 37 * MB);// 24 MB: Q(16) + K(4) + V(4)
  short* O      = xb;                    // alias: xb dead after QKV GEMM

  short* Qb = QKVb;
  short* Kb = QKVb + QOFF;
  short* Vt = QKVb + QOFF + KOFF;

  rope_tab_k<<<(SLEN * 64 + 255) / 256, 256, 0, stream>>>(rope);
  cast_bf16_k<<<(MROWS * EMB / 4 + 255) / 256, 256, 0, stream>>>(x, xb, MROWS * EMB);

  dim3 tb(32, 8);
  transpose_cast_k<<<dim3(2048 / 32, 2048 / 32), tb, 0, stream>>>(wq, wqkvT, 2048, 2048);
  transpose_cast_k<<<dim3(512 / 32, 2048 / 32), tb, 0, stream>>>(wk, wqkvT + 2048 * 2048, 2048, 512);
  transpose_cast_k<<<dim3(512 / 32, 2048 / 32), tb, 0, stream>>>(wv, wqkvT + 2560 * 2048, 2048, 512);
  transpose_cast_k<<<dim3(2048 / 32, 2048 / 32), tb, 0, stream>>>(wo, woT, 2048, 2048);

  gemm_qkv256_k<<<dim3(3072 / 256, MROWS / 256), 512, 0, stream>>>(xb, wqkvT, QKVb, rope);

  flash_k<<<dim3(SLEN / 128, BSZ * NH), 512, 0, stream>>>(Qb, Kb, Vt, O);

  gemm_bt_k<<<dim3(2048 / BN, MROWS / BM), 256, 0, stream>>>(O, woT, out, MROWS, 2048, 2048);
}

// Round 8
// 215.786 us; speedup vs baseline: 1.1543x; 1.1543x over previous
//
#include <hip/hip_runtime.h>

#define EMB 2048
#define NH 16
#define NKV 4
#define HD 128
#define SLEN 2048
#define BSZ 2
#define MROWS (BSZ * SLEN) // 4096

// element offsets within the fused QKV output buffer
#define QOFF (BSZ * NH * SLEN * HD)   // 8388608
#define KOFF (BSZ * NKV * SLEN * HD)  // 2097152

typedef __attribute__((ext_vector_type(8))) short bf16x8;
typedef __attribute__((ext_vector_type(4))) float f32x4;
typedef __attribute__((ext_vector_type(2))) float f32x2;
typedef __attribute__((ext_vector_type(4))) short s16x4;

__device__ __forceinline__ short f2bf(float f) {
  union { float f; unsigned u; } v; v.f = f;
  unsigned r = (v.u + 0x7fffu + ((v.u >> 16) & 1u)) >> 16;
  return (short)r;
}

// ---------------- RoPE cos/sin table: [SLEN][64] ----------------
__global__ void rope_tab_k(f32x2* __restrict__ tab) {
  int i = blockIdx.x * blockDim.x + threadIdx.x;
  if (i >= SLEN * 64) return;
  int s = i >> 6, j = i & 63;
  float freq = exp2f(-(float)j * (13.287712379549449f / 64.0f));
  float ang = (float)s * freq;
  float sv, cv;
  sincosf(ang, &sv, &cv);
  f32x2 cs; cs[0] = cv; cs[1] = sv;
  tab[i] = cs;
}

// ---------------- fp32 -> bf16 cast (vectorized) ----------------
__global__ void cast_bf16_k(const float* __restrict__ in, short* __restrict__ outp, int n) {
  int i = (blockIdx.x * blockDim.x + threadIdx.x) * 4;
  if (i >= n) return;
  f32x4 v = *(const f32x4*)(in + i);
  s16x4 r;
#pragma unroll
  for (int k = 0; k < 4; ++k) r[k] = f2bf(v[k]);
  *(s16x4*)(outp + i) = r;
}

// ---------------- transpose + cast: in (R,C) fp32 -> out (C,R) bf16 ----------------
__global__ void transpose_cast_k(const float* __restrict__ in, short* __restrict__ outp,
                                 int R, int C) {
  __shared__ float t[32][33];
  int c0 = blockIdx.x * 32, r0 = blockIdx.y * 32;
  int tx = threadIdx.x, ty = threadIdx.y; // 32 x 8
#pragma unroll
  for (int i = 0; i < 4; ++i)
    t[ty + i * 8][tx] = in[(size_t)(r0 + ty + i * 8) * C + (c0 + tx)];
  __syncthreads();
#pragma unroll
  for (int i = 0; i < 4; ++i)
    outp[(size_t)(c0 + ty + i * 8) * R + (r0 + tx)] = f2bf(t[tx][ty + i * 8]);
}

// ---------------- GEMM: C(M,N) = A(M,K) * Bt(N,K)^T, bf16 MFMA ----------------
#define BM 128
#define BN 128
#define BK 32

#define GLL16(g, l)                                                        \
  __builtin_amdgcn_global_load_lds(                                        \
      (const __attribute__((address_space(1))) void*)(g),                  \
      (__attribute__((address_space(3))) void*)(l), 16, 0, 0)

// EPI: 0 = fp32 store to Cf (row-major M x N)
//      5 = fused QKV epilogue: gc<2048 Q (RoPE+scale), gc<2560 K (RoPE),
//          else V (transposed store). Regions tile-aligned -> wave-uniform.
template <int EPI>
__global__ __launch_bounds__(256, 2) void gemm_bt_k(
    const short* __restrict__ A, const short* __restrict__ Bt,
    float* __restrict__ Cf, short* __restrict__ Cb,
    int M, int N, int K, const f32x2* __restrict__ rope) {
  __shared__ short lA[2][BM * BK];
  __shared__ short lB[2][BN * BK];
  int tid = threadIdx.x;
  int lane = tid & 63, wid = tid >> 6;
  int m0 = blockIdx.y * BM, n0 = blockIdx.x * BN;
  int wr = (wid >> 1) * 64, wc = (wid & 1) * 64;
  int l16 = lane & 15, lk = (lane >> 4) * 8;
  (void)M;

  auto stage = [&](int buf, int k0) {
    const short* ga = A + (size_t)m0 * K + k0;
    const short* gb = Bt + (size_t)n0 * K + k0;
#pragma unroll
    for (int i = 0; i < 2; ++i) {
      int cidx = i * 256 + tid;
      int row = cidx >> 2, c8 = (cidx & 3) << 3;
      GLL16(ga + (size_t)row * K + c8, &lA[buf][(size_t)(i * 256 + (tid & 192)) * 8]);
      GLL16(gb + (size_t)row * K + c8, &lB[buf][(size_t)(i * 256 + (tid & 192)) * 8]);
    }
  };

  f32x4 acc[4][4] = {};
  stage(0, 0);
  asm volatile("s_waitcnt vmcnt(0)" ::: "memory");
  __syncthreads();
  int nk = K / BK;
  for (int t = 0; t < nk; ++t) {
    int buf = t & 1;
    if (t + 1 < nk) stage(buf ^ 1, (t + 1) * BK);
    bf16x8 af[4], bfv[4];
#pragma unroll
    for (int m = 0; m < 4; ++m)
      af[m] = *(const bf16x8*)&lA[buf][(wr + m * 16 + l16) * BK + lk];
#pragma unroll
    for (int n = 0; n < 4; ++n)
      bfv[n] = *(const bf16x8*)&lB[buf][(wc + n * 16 + l16) * BK + lk];
#pragma unroll
    for (int m = 0; m < 4; ++m)
#pragma unroll
      for (int n = 0; n < 4; ++n)
        acc[m][n] = __builtin_amdgcn_mfma_f32_16x16x32_bf16(af[m], bfv[n], acc[m][n], 0, 0, 0);
    asm volatile("s_waitcnt vmcnt(0)" ::: "memory");
    __syncthreads();
  }

  const float SCL2E = 0.08838834764831845f * 1.4426950408889634f;
  // epilogue: C/D layout col = lane&15, row = (lane>>4)*4 + reg
#pragma unroll
  for (int m = 0; m < 4; ++m) {
#pragma unroll
    for (int n = 0; n < 4; ++n) {
#pragma unroll
      for (int j = 0; j < 4; ++j) {
        int gm = m0 + wr + m * 16 + (lane >> 4) * 4 + j;
        int gc = n0 + wc + n * 16 + l16;
        float v = acc[m][n][j];
        if constexpr (EPI == 0) {
          Cf[(size_t)gm * N + gc] = v;
        } else { // EPI == 5: fused QKV
          int pos = gm & (SLEN - 1), bb = gm >> 11;
          if (gc < 2560) { // Q or K: RoPE
            float p = __shfl_xor(v, 1); // partner column (d^1), same row
            bool isq = gc < 2048;
            int gcc = isq ? gc : gc - 2048;
            int head = gcc >> 7, d = gcc & 127, j2 = d >> 1;
            f32x2 cs = rope[pos * 64 + j2];
            float ov; int od;
            if ((d & 1) == 0) { ov = v * cs[0] - p * cs[1]; od = j2; }
            else              { ov = p * cs[1] + v * cs[0]; od = j2 + 64; }
            if (isq) ov *= SCL2E; // fold attn scale*log2e into Q
            size_t idx = isq
                ? (((size_t)(bb * NH + head) * SLEN + pos) * HD + od)
                : ((size_t)QOFF + ((size_t)(bb * NKV + head) * SLEN + pos) * HD + od);
            Cb[idx] = f2bf(ov);
          } else { // V: transposed per (b,kv): [HD][S]
            int gcc = gc - 2560;
            int head = gcc >> 7, d = gcc & 127;
            Cb[(size_t)QOFF + KOFF + ((size_t)(bb * NKV + head) * HD + d) * SLEN + pos] = f2bf(v);
          }
        }
      }
    }
  }
}

// ---------------- flash attention: balanced pairs + 4-deep counted pipeline --
// 256 blocks (8 x 32), 512 thr. Each block processes TWO q-tiles (qtA=15-x,
// qtB=x) -> exactly 34 KV-tile units per block: zero causal imbalance, 1
// block/CU. KV staged into a 4-deep LDS ring via global_load_lds; per tile
// only vmcnt(8) + raw s_barrier (counted, T3/T4 - never a full drain except
// the 2-tile tail). stage(tt+3) issued after the top-of-tt barrier targets
// ring slot (tt-1)&3 whose readers all finished before that barrier (no WAR).
// Compute body (swapped QK^T, in-lane softmax, P via fenced LDS) = R5/R6.
__global__ __launch_bounds__(512, 2) void flash_k(
    const short* __restrict__ Qb, const short* __restrict__ Kb,
    const short* __restrict__ Vt, short* __restrict__ O) {
  __shared__ short lK[4][64 * 128];   // 4 x 16KB: 64 key rows x 256B
  __shared__ short lV[4][128 * 64];   // 4 x 16KB: 128 dim rows x 128B
  __shared__ short Plds[8][16][64];   // per-wave P: 16 rows x 128B

  int tid = threadIdx.x, lane = tid & 63, wid = tid >> 6;
  int bh = blockIdx.y;
  int b = bh >> 4, h = bh & 15, kv = h & 3; // jnp.tile => h % NKV
  int l16 = lane & 15, lk4 = lane >> 4;
  int qtA = 15 - (int)blockIdx.x;          // 8..15 (heavy)
  int qtB = (int)blockIdx.x;               // 0..7  (light)
  int ntA = 2 * (qtA + 1);
  int ntot = ntA + 2 * (qtB + 1);          // == 34 for every block

  const short* qptr = Qb + (size_t)(b * NH + h) * SLEN * HD;
  const char* kg = (const char*)(Kb + (size_t)(b * NKV + kv) * SLEN * HD);
  const char* vg = (const char*)(Vt + (size_t)(b * NKV + kv) * HD * SLEN);

  int qbw = qtA * 128 + wid * 16; // current segment's q-row base for this wave
  bf16x8 aq[4];
#pragma unroll
  for (int c = 0; c < 4; ++c)
    aq[c] = *(const bf16x8*)(qptr + (size_t)(qbw + l16) * HD + c * 32 + lk4 * 8);

  f32x4 o[8] = {};
  float m = -__builtin_inff();
  float lsum = 0.0f;

  char* myP = (char*)&Plds[wid][0][0];
  int swz = (l16 & 7) << 4;   // 3-bit (P and V: 128B rows)
  int swzk = l16 << 4;        // 4-bit (K: 256B rows)

  auto stageKV = [&](int buf, int k0) {
#pragma unroll
    for (int r = 0; r < 2; ++r) { // K: 16KB = 2 rounds x 512 thr x 16B
      int X = tid * 16 + r * 8192;
      int row = X >> 8, cb = X & 255;
      GLL16(kg + (size_t)(k0 + row) * 256 + (cb ^ ((row & 15) << 4)),
            (char*)&lK[buf][0] + X);
    }
#pragma unroll
    for (int r = 0; r < 2; ++r) { // V: 16KB
      int X = tid * 16 + r * 8192;
      int row = X >> 7, cb = X & 127;
      GLL16(vg + (size_t)row * (SLEN * 2) + k0 * 2 + (cb ^ ((row & 7) << 4)),
            (char*)&lV[buf][0] + X);
    }
  };
  auto k0_of = [&](int t) { return (t < ntA ? t : t - ntA) * 64; };

  auto finalize = [&]() {
    float ls = lsum;
    ls += __shfl_xor(ls, 16);
    ls += __shfl_xor(ls, 32);
    float inv = 1.0f / ls;
    size_t ro = ((size_t)(b * SLEN + qbw + l16)) * (NH * HD) + h * HD;
#pragma unroll
    for (int dt = 0; dt < 8; ++dt) {
      s16x4 r;
#pragma unroll
      for (int j = 0; j < 4; ++j) r[j] = f2bf(o[dt][j] * inv);
      *(s16x4*)(O + ro + dt * 16 + lk4 * 4) = r;
    }
  };

  // prologue: fill 3 ring slots (ntot >= 18 always)
  stageKV(0, k0_of(0));
  stageKV(1, k0_of(1));
  stageKV(2, k0_of(2));

  for (int tt = 0; tt < ntot; ++tt) {
    // counted wait: oldest in-flight tile (tt) done; keep up to 8 in flight
    int rem = ntot - 1 - tt;
    if (rem >= 2)      asm volatile("s_waitcnt vmcnt(8)" ::: "memory");
    else if (rem == 1) asm volatile("s_waitcnt vmcnt(4)" ::: "memory");
    else               asm volatile("s_waitcnt vmcnt(0)" ::: "memory");
    __builtin_amdgcn_s_barrier();
    __builtin_amdgcn_sched_barrier(0);

    if (tt == ntA) { // segment switch: flush A, reset state, load Q for B
      finalize();
#pragma unroll
      for (int dt = 0; dt < 8; ++dt) o[dt] = (f32x4){0.f, 0.f, 0.f, 0.f};
      m = -__builtin_inff();
      lsum = 0.0f;
      qbw = qtB * 128 + wid * 16;
#pragma unroll
      for (int c = 0; c < 4; ++c)
        aq[c] = *(const bf16x8*)(qptr + (size_t)(qbw + l16) * HD + c * 32 + lk4 * 8);
    }

    int k0 = k0_of(tt);
    int buf = tt & 3;
    if (k0 < qbw + 16) { // this wave has unmasked keys in this tile
      const char* Kbase = (const char*)&lK[buf][0];
      const char* Vbase = (const char*)&lV[buf][0];
      // ---- QK^T (swapped): s[t][j] = S[key=k0+t*16+lk4*4+j][q=qbw+l16] ----
      f32x4 s[4] = {};
      __builtin_amdgcn_s_setprio(1);
#pragma unroll
      for (int c = 0; c < 4; ++c) {
#pragma unroll
        for (int t = 0; t < 4; ++t) {
          bf16x8 bk = *(const bf16x8*)(Kbase + (t * 16 + l16) * 256 + ((c * 64 + lk4 * 16) ^ swzk));
          s[t] = __builtin_amdgcn_mfma_f32_16x16x32_bf16(bk, aq[c], s[t], 0, 0, 0);
        }
      }
      __builtin_amdgcn_s_setprio(0);
      // ---- in-lane softmax ----
      float x[16];
#pragma unroll
      for (int t = 0; t < 4; ++t)
#pragma unroll
        for (int j = 0; j < 4; ++j) x[t * 4 + j] = s[t][j];
      if (k0 + 63 > qbw) { // tile touches this wave's causal diagonal
        int kq = k0 + lk4 * 4 - qbw - l16;
#pragma unroll
        for (int t = 0; t < 4; ++t)
#pragma unroll
          for (int j = 0; j < 4; ++j)
            if (kq + t * 16 + j > 0) x[t * 4 + j] = -3.0e38f;
      }
      float a0 = fmaxf(x[0], x[1]), a1 = fmaxf(x[2], x[3]);
      float a2 = fmaxf(x[4], x[5]), a3 = fmaxf(x[6], x[7]);
      float a4 = fmaxf(x[8], x[9]), a5 = fmaxf(x[10], x[11]);
      float a6 = fmaxf(x[12], x[13]), a7 = fmaxf(x[14], x[15]);
      float b0 = fmaxf(fmaxf(a0, a1), fmaxf(a2, a3));
      float b1 = fmaxf(fmaxf(a4, a5), fmaxf(a6, a7));
      float tm = fmaxf(b0, b1);
      tm = fmaxf(tm, __shfl_xor(tm, 16));
      tm = fmaxf(tm, __shfl_xor(tm, 32));
      float mn = fmaxf(m, tm);
      if (!__all(tm <= m + 8.0f)) { // T13 defer-rescale
        float f = __builtin_amdgcn_exp2f(m - mn);
        m = mn;
        lsum *= f;
#pragma unroll
        for (int dt = 0; dt < 8; ++dt) o[dt] *= f;
      }
      float psum = 0.0f;
#pragma unroll
      for (int t = 0; t < 4; ++t) {
        float p0 = __builtin_amdgcn_exp2f(x[t * 4 + 0] - m);
        float p1 = __builtin_amdgcn_exp2f(x[t * 4 + 1] - m);
        float p2 = __builtin_amdgcn_exp2f(x[t * 4 + 2] - m);
        float p3 = __builtin_amdgcn_exp2f(x[t * 4 + 3] - m);
        psum += (p0 + p1) + (p2 + p3);
        unsigned lo, hi;
        asm("v_cvt_pk_bf16_f32 %0, %1, %2" : "=v"(lo) : "v"(p0), "v"(p1));
        asm("v_cvt_pk_bf16_f32 %0, %1, %2" : "=v"(hi) : "v"(p2), "v"(p3));
        unsigned long long dw = ((unsigned long long)hi << 32) | lo;
        *(unsigned long long*)(myP + ((l16 * 128 + t * 32 + lk4 * 8) ^ swz)) = dw;
      }
      lsum += psum;
      // ---- ORDERING FENCE (rule #18): drain P ds_writes, pin reads below --
      asm volatile("s_waitcnt lgkmcnt(0)" ::: "memory");
      __builtin_amdgcn_sched_barrier(0);
      // ---- PV (swapped): o[dt][j] = O[q=qbw+l16][d=dt*16+lk4*4+j] ----
      __builtin_amdgcn_s_setprio(1);
#pragma unroll
      for (int hh = 0; hh < 2; ++hh) {
        bf16x8 pa = *(const bf16x8*)(myP + ((l16 * 128 + hh * 64 + lk4 * 16) ^ swz));
#pragma unroll
        for (int dt = 0; dt < 8; ++dt) {
          bf16x8 bv = *(const bf16x8*)(Vbase + (dt * 16 + l16) * 128 + ((hh * 64 + lk4 * 16) ^ swz));
          o[dt] = __builtin_amdgcn_mfma_f32_16x16x32_bf16(bv, pa, o[dt], 0, 0, 0);
        }
      }
      __builtin_amdgcn_s_setprio(0);
    }
    // issue stage for tile tt+3 into ring slot (tt+3)&3 == (tt-1)&3, whose
    // readers finished before this iteration's opening barrier (no WAR race).
    if (tt + 3 < ntot) stageKV((tt + 3) & 3, k0_of(tt + 3));
  }
  finalize(); // segment B
}

extern "C" void kernel_launch(void* const* d_in, const int* in_sizes, int n_in,
                              void* d_out, int out_size, void* d_ws, size_t ws_size,
                              hipStream_t stream) {
  const float* x  = (const float*)d_in[0];
  const float* wq = (const float*)d_in[1];
  const float* wk = (const float*)d_in[2];
  const float* wv = (const float*)d_in[3];
  const float* wo = (const float*)d_in[4];
  float* out = (float*)d_out;
  char* ws = (char*)d_ws;
  (void)in_sizes; (void)n_in; (void)out_size; (void)ws_size;

  const size_t MB = 1024 * 1024;
  f32x2* rope   = (f32x2*)(ws);          // 1 MB
  short* xb     = (short*)(ws + 1 * MB); // 16 MB (reused as O)
  short* wqkvT  = (short*)(ws + 17 * MB);// 12 MB: [3072][2048] bf16 B^T
  short* woT    = (short*)(ws + 29 * MB);// 8 MB
  short* QKVb   = (short*)(ws + 37 * MB);// 24 MB: Q(16) + K(4) + V(4)
  short* O      = xb;                    // alias: xb dead after QKV GEMM

  short* Qb = QKVb;
  short* Kb = QKVb + QOFF;
  short* Vt = QKVb + QOFF + KOFF;

  rope_tab_k<<<(SLEN * 64 + 255) / 256, 256, 0, stream>>>(rope);
  cast_bf16_k<<<(MROWS * EMB / 4 + 255) / 256, 256, 0, stream>>>(x, xb, MROWS * EMB);

  dim3 tb(32, 8);
  transpose_cast_k<<<dim3(2048 / 32, 2048 / 32), tb, 0, stream>>>(wq, wqkvT, 2048, 2048);
  transpose_cast_k<<<dim3(512 / 32, 2048 / 32), tb, 0, stream>>>(wk, wqkvT + 2048 * 2048, 2048, 512);
  transpose_cast_k<<<dim3(512 / 32, 2048 / 32), tb, 0, stream>>>(wv, wqkvT + 2560 * 2048, 2048, 512);
  transpose_cast_k<<<dim3(2048 / 32, 2048 / 32), tb, 0, stream>>>(wo, woT, 2048, 2048);

  gemm_bt_k<5><<<dim3(3072 / BN, MROWS / BM), 256, 0, stream>>>(xb, wqkvT, nullptr, QKVb, MROWS, 3072, 2048, rope);

  flash_k<<<dim3(8, BSZ * NH), 512, 0, stream>>>(Qb, Kb, Vt, O);

  gemm_bt_k<0><<<dim3(2048 / BN, MROWS / BM), 256, 0, stream>>>(O, woT, out, nullptr, MROWS, 2048, 2048, rope);
}